// Round 1
// baseline (312.680 us; speedup 1.0000x reference)
//
#include <hip/hip_runtime.h>
#include <hip/hip_bf16.h>

#define B_  8
#define H_  512
#define L_  2048
#define D2_ 32
#define NC_ 16
#define LC_ 128   // L_/NC_

typedef __attribute__((ext_vector_type(8))) short short8;   // 8 bf16 (4 VGPRs)
typedef __attribute__((ext_vector_type(4))) float float4v;  // 4 fp32 acc

__device__ __forceinline__ float gelu_exact(float x) {
    return 0.5f * x * (1.0f + erff(x * 0.70710678118654752f));
}

// ---------------- kernel 0: cast W (512x512 f32) -> bf16 ----------------
__global__ void cast_w_kernel(const float* __restrict__ W, __hip_bfloat16* __restrict__ Wb) {
    int tid = blockIdx.x * 256 + threadIdx.x;   // 262144 threads
    Wb[tid] = __float2bfloat16(W[tid]);
}

// ---------------- kernel 1: f[h,l], k0[h,l] ----------------
// f[h,l]  = 2T * sum_d b*c * exp(-|a| z) cos(theta z)
// k0[h,l] = 2  * sum_d c*x0 * exp(-|a| z) cos(theta z)
__global__ void fk_kernel(const float* __restrict__ a, const float* __restrict__ th,
                          const float* __restrict__ bb, const float* __restrict__ cc,
                          const float* __restrict__ x0, float2* __restrict__ FK) {
    int tid = blockIdx.x * 256 + threadIdx.x;   // H_*L_ threads
    int h = tid >> 11;
    int l = tid & (L_ - 1);
    const float T = 1.0f / (float)(L_ - 1);
    float z = T * (float)l;
    float facc = 0.f, kacc = 0.f;
    #pragma unroll
    for (int d = 0; d < D2_; ++d) {
        float av = a[h * D2_ + d];
        float tv = th[h * D2_ + d];
        float e = __expf(-fabsf(av) * z) * __cosf(tv * z);
        facc = fmaf(bb[h * D2_ + d] * cc[h * D2_ + d], e, facc);
        kacc = fmaf(cc[h * D2_ + d] * x0[h * D2_ + d], e, kacc);
    }
    FK[tid] = make_float2(2.0f * T * facc, 2.0f * kacc);
}

// ---------------- kernel 2 (Pass A): per-(b,h,d) scan -> chunk carries ----------------
__global__ __launch_bounds__(256) void scan_carry_kernel(
        const float* __restrict__ u, const float* __restrict__ a,
        const float* __restrict__ th, float2* __restrict__ SC) {
    int tid = blockIdx.x * 256 + threadIdx.x;   // B_*H_*D2_ = 131072 threads
    int d  = tid & (D2_ - 1);
    int bh = tid >> 5;
    int h  = bh & (H_ - 1);
    const float T = 1.0f / (float)(L_ - 1);
    float aa  = -fabsf(a[h * D2_ + d]);
    float ea  = __expf(aa * T);
    float tT  = th[h * D2_ + d] * T;
    float wr  = ea * __cosf(tT);
    float wi  = ea * __sinf(tT);
    const float* ur = u + (size_t)bh * L_;
    float sr = 0.f, si = 0.f;
    for (int c = 0; c < NC_; ++c) {
        #pragma unroll 8
        for (int i = 0; i < LC_; ++i) {
            float ul = ur[c * LC_ + i];
            float nr = fmaf(sr, wr, fmaf(-si, wi, ul));
            float ni = fmaf(sr, wi, si * wr);
            sr = nr; si = ni;
        }
        if (c + 1 < NC_)   // carry INTO chunk c+1
            SC[((size_t)bh * NC_ + (c + 1)) * D2_ + d] = make_float2(sr, si);
    }
}

// ---------------- kernel 3 (Pass B): full scan per chunk, fused epilogue ----------------
__global__ __launch_bounds__(256) void scan_full_kernel(
        const float* __restrict__ u, const float* __restrict__ a,
        const float* __restrict__ th, const float* __restrict__ bb,
        const float* __restrict__ cc, const float* __restrict__ Dp,
        const float2* __restrict__ FK, const float2* __restrict__ SC,
        __hip_bfloat16* __restrict__ yT) {
    int c = blockIdx.x;                       // 0..15
    int b = blockIdx.z;                       // 0..7
    int h = blockIdx.y * 256 + threadIdx.x;   // 0..511
    int bh = b * H_ + h;
    const float T = 1.0f / (float)(L_ - 1);

    float wr[D2_], wi[D2_], q[D2_], sr[D2_], si[D2_];
    float qsum = 0.f;
    #pragma unroll
    for (int d = 0; d < D2_; ++d) {
        float aa = -fabsf(a[h * D2_ + d]);
        float ea = __expf(aa * T);
        float tT = th[h * D2_ + d] * T;
        wr[d] = ea * __cosf(tT);
        wi[d] = ea * __sinf(tT);
        q[d]  = bb[h * D2_ + d] * cc[h * D2_ + d];
        qsum += q[d];
    }
    float f0 = 2.0f * T * qsum;               // f[h,0]

    #pragma unroll
    for (int d = 0; d < D2_; ++d) {
        if (c == 0) { sr[d] = 0.f; si[d] = 0.f; }
        else {
            float2 s = SC[((size_t)bh * NC_ + c) * D2_ + d];
            sr[d] = s.x; si[d] = s.y;
        }
    }

    float u0 = u[(size_t)bh * L_];
    float Dh = Dp[h];
    const float*  ur  = u  + (size_t)bh * L_ + c * LC_;
    const float2* fkr = FK + (size_t)h  * L_ + c * LC_;
    __hip_bfloat16* yr = yT + ((size_t)b * L_ + c * LC_) * H_ + h;

    for (int i = 0; i < LC_; ++i) {
        float ul = ur[i];
        float2 fk = fkr[i];
        float dta[4] = {0.f, 0.f, 0.f, 0.f};
        #pragma unroll
        for (int d = 0; d < D2_; ++d) {
            float nr = fmaf(sr[d], wr[d], fmaf(-si[d], wi[d], ul));
            float ni = fmaf(sr[d], wi[d], si[d] * wr[d]);
            sr[d] = nr; si[d] = ni;
            dta[d & 3] = fmaf(q[d], nr, dta[d & 3]);
        }
        float dot = (dta[0] + dta[1]) + (dta[2] + dta[3]);
        float y = fmaf(2.0f * T, dot, fk.y)           // conv + k0
                  - 0.5f * (f0 * ul + fk.x * u0)      // trapezoid correction
                  + Dh * ul;                          // skip D*u
        yr[(size_t)i * H_] = __float2bfloat16(gelu_exact(y));
    }
}

// ---------------- kernel 4: out[b,h,l] = sum_f W[h,f] * yT[b,l,f] + bias[h] ----------------
// A = W (M=512 x K=512), B^T = yT[b] (N=2048 rows x K), C 128x128 tiles, bf16 MFMA.
__global__ __launch_bounds__(256) void gemm_kernel(
        const __hip_bfloat16* __restrict__ Wb, const __hip_bfloat16* __restrict__ yT,
        const float* __restrict__ bias, float* __restrict__ out) {
    __shared__ __align__(16) short As[128 * 32];
    __shared__ __align__(16) short Bs[128 * 32];
    int l0 = blockIdx.x * 128;      // N tile
    int h0 = blockIdx.y * 128;      // M tile
    int b  = blockIdx.z;
    int t    = threadIdx.x;
    int lane = t & 63, wave = t >> 6;
    int m_off = (wave >> 1) * 64, n_off = (wave & 1) * 64;
    int quad = lane >> 4, ln = lane & 15;

    float4v acc[4][4];
    #pragma unroll
    for (int mt = 0; mt < 4; ++mt)
        #pragma unroll
        for (int nt = 0; nt < 4; ++nt)
            acc[mt][nt] = (float4v){0.f, 0.f, 0.f, 0.f};

    const short* Wg = (const short*)Wb;
    const short* Yg = (const short*)(yT + (size_t)b * L_ * H_);

    int r  = t >> 2;      // 0..63
    int qd = t & 3;       // 16B chunk within 64B row

    for (int kt = 0; kt < 16; ++kt) {
        int k0 = kt * 32;
        // stage A (W tile 128 rows x 32 k) and B (yT tile 128 rows(l) x 32 k)
        ((uint4*)As)[r * 4 + qd]        = *(const uint4*)(Wg + (h0 + r)      * 512 + k0 + qd * 8);
        ((uint4*)As)[(r + 64) * 4 + qd] = *(const uint4*)(Wg + (h0 + r + 64) * 512 + k0 + qd * 8);
        ((uint4*)Bs)[r * 4 + qd]        = *(const uint4*)(Yg + (size_t)(l0 + r)      * 512 + k0 + qd * 8);
        ((uint4*)Bs)[(r + 64) * 4 + qd] = *(const uint4*)(Yg + (size_t)(l0 + r + 64) * 512 + k0 + qd * 8);
        __syncthreads();

        short8 af[4], bf[4];
        #pragma unroll
        for (int mt = 0; mt < 4; ++mt)
            af[mt] = *(const short8*)&As[(m_off + mt * 16 + ln) * 32 + quad * 8];
        #pragma unroll
        for (int nt = 0; nt < 4; ++nt)
            bf[nt] = *(const short8*)&Bs[(n_off + nt * 16 + ln) * 32 + quad * 8];
        #pragma unroll
        for (int mt = 0; mt < 4; ++mt)
            #pragma unroll
            for (int nt = 0; nt < 4; ++nt)
                acc[mt][nt] = __builtin_amdgcn_mfma_f32_16x16x32_bf16(
                    af[mt], bf[nt], acc[mt][nt], 0, 0, 0);
        __syncthreads();
    }

    // epilogue: D layout col=lane&15, row=quad*4+reg
    #pragma unroll
    for (int mt = 0; mt < 4; ++mt) {
        #pragma unroll
        for (int nt = 0; nt < 4; ++nt) {
            int hh = h0 + m_off + mt * 16 + quad * 4;
            int ll = l0 + n_off + nt * 16 + ln;
            #pragma unroll
            for (int r2 = 0; r2 < 4; ++r2)
                out[((size_t)(b * H_ + hh + r2)) * L_ + ll] = acc[mt][nt][r2] + bias[hh + r2];
        }
    }
}

extern "C" void kernel_launch(void* const* d_in, const int* in_sizes, int n_in,
                              void* d_out, int out_size, void* d_ws, size_t ws_size,
                              hipStream_t stream) {
    const float* u    = (const float*)d_in[0];
    const float* a    = (const float*)d_in[1];
    const float* th   = (const float*)d_in[2];
    const float* bb   = (const float*)d_in[3];
    const float* cc   = (const float*)d_in[4];
    const float* x0   = (const float*)d_in[5];
    const float* Dp   = (const float*)d_in[6];
    const float* W    = (const float*)d_in[7];
    const float* bias = (const float*)d_in[8];
    float* out = (float*)d_out;

    char* ws = (char*)d_ws;
    float2* FK          = (float2*)ws;                                  // 8 MB
    float2* SC          = (float2*)(ws + 8u * 1024 * 1024);             // 16 MB
    __hip_bfloat16* yT  = (__hip_bfloat16*)(ws + 24u * 1024 * 1024);    // 16 MB
    __hip_bfloat16* Wb  = (__hip_bfloat16*)(ws + 40u * 1024 * 1024);    // 0.5 MB

    hipLaunchKernelGGL(cast_w_kernel,    dim3(1024),       dim3(256), 0, stream, W, Wb);
    hipLaunchKernelGGL(fk_kernel,        dim3(4096),       dim3(256), 0, stream, a, th, bb, cc, x0, FK);
    hipLaunchKernelGGL(scan_carry_kernel,dim3(512),        dim3(256), 0, stream, u, a, th, SC);
    hipLaunchKernelGGL(scan_full_kernel, dim3(16, 2, 8),   dim3(256), 0, stream,
                       u, a, th, bb, cc, Dp, FK, SC, yT);
    hipLaunchKernelGGL(gemm_kernel,      dim3(16, 4, 8),   dim3(256), 0, stream, Wb, yT, bias, out);
}

// Round 2
// 260.837 us; speedup vs baseline: 1.1988x; 1.1988x over previous
//
#include <hip/hip_runtime.h>
#include <hip/hip_bf16.h>

#define B_  8
#define H_  512
#define L_  2048
#define D2_ 32
#define NC_ 16
#define LC_ 128   // L_/NC_

typedef __attribute__((ext_vector_type(8))) short short8;   // 8 bf16 (4 VGPRs)
typedef __attribute__((ext_vector_type(4))) float float4v;  // 4 fp32 acc

__device__ __forceinline__ float gelu_exact(float x) {
    return 0.5f * x * (1.0f + erff(x * 0.70710678118654752f));
}

// ---------------- kernel 0: cast W (512x512 f32) -> bf16 ----------------
__global__ void cast_w_kernel(const float* __restrict__ W, __hip_bfloat16* __restrict__ Wb) {
    int tid = blockIdx.x * 256 + threadIdx.x;   // 262144 threads
    Wb[tid] = __float2bfloat16(W[tid]);
}

// ---------------- kernel 1: f[h,l], k0[h,l] ----------------
__global__ void fk_kernel(const float* __restrict__ a, const float* __restrict__ th,
                          const float* __restrict__ bb, const float* __restrict__ cc,
                          const float* __restrict__ x0, float2* __restrict__ FK) {
    int tid = blockIdx.x * 256 + threadIdx.x;   // H_*L_ threads
    int h = tid >> 11;
    int l = tid & (L_ - 1);
    const float T = 1.0f / (float)(L_ - 1);
    float z = T * (float)l;
    float facc = 0.f, kacc = 0.f;
    #pragma unroll
    for (int d = 0; d < D2_; ++d) {
        float av = a[h * D2_ + d];
        float tv = th[h * D2_ + d];
        float e = __expf(-fabsf(av) * z) * __cosf(tv * z);
        facc = fmaf(bb[h * D2_ + d] * cc[h * D2_ + d], e, facc);
        kacc = fmaf(cc[h * D2_ + d] * x0[h * D2_ + d], e, kacc);
    }
    FK[tid] = make_float2(2.0f * T * facc, 2.0f * kacc);
}

// ---------------- kernel 2a (Pass A): chunk-local scans from zero state ----------------
// thread (bh, c, d): E[(bh*NC+c)*D2+d] = sum_{i} w^{LC-1-i} u[bh, c*LC+i]
__global__ __launch_bounds__(256) void scan_chunk_kernel(
        const float* __restrict__ u, const float* __restrict__ a,
        const float* __restrict__ th, float2* __restrict__ E) {
    int tid = blockIdx.x * 256 + threadIdx.x;   // B_*H_*D2_*NC_ = 2,097,152 threads
    int d  = tid & (D2_ - 1);
    int c  = (tid >> 5) & (NC_ - 1);
    int bh = tid >> 9;
    int h  = bh & (H_ - 1);
    const float T = 1.0f / (float)(L_ - 1);
    float aa  = -fabsf(a[h * D2_ + d]);
    float ea  = __expf(aa * T);
    float tT  = th[h * D2_ + d] * T;
    float wr  = ea * __cosf(tT);
    float wi  = ea * __sinf(tT);
    const float* ur = u + (size_t)bh * L_ + c * LC_;
    float sr = 0.f, si = 0.f;
    #pragma unroll 8
    for (int i = 0; i < LC_; ++i) {
        float ul = ur[i];
        float nr = fmaf(sr, wr, fmaf(-si, wi, ul));
        float ni = fmaf(sr, wi, si * wr);
        sr = nr; si = ni;
    }
    E[((size_t)bh * NC_ + c) * D2_ + d] = make_float2(sr, si);
}

// ---------------- kernel 2b: combine chunk-local states into carries ----------------
// per (b,h,d): S_{c+1} = w^LC * S_c + E[c];  SC[c] = state entering chunk c (c>=1)
__global__ __launch_bounds__(256) void combine_kernel(
        const float* __restrict__ a, const float* __restrict__ th,
        const float2* __restrict__ E, float2* __restrict__ SC) {
    int tid = blockIdx.x * 256 + threadIdx.x;   // B_*H_*D2_ = 131072 threads
    int d  = tid & (D2_ - 1);
    int bh = tid >> 5;
    int h  = bh & (H_ - 1);
    const float T = 1.0f / (float)(L_ - 1);
    float aa  = -fabsf(a[h * D2_ + d]);
    float eC  = __expf(aa * T * (float)LC_);
    float tC  = th[h * D2_ + d] * T * (float)LC_;
    float Wr  = eC * __cosf(tC);
    float Wi  = eC * __sinf(tC);
    float sr = 0.f, si = 0.f;
    #pragma unroll
    for (int c = 0; c < NC_; ++c) {
        float2 e = E[((size_t)bh * NC_ + c) * D2_ + d];
        float nr = fmaf(sr, Wr, fmaf(-si, Wi, e.x));
        float ni = fmaf(sr, Wi, fmaf(si, Wr, e.y));
        sr = nr; si = ni;
        if (c + 1 < NC_)
            SC[((size_t)bh * NC_ + (c + 1)) * D2_ + d] = make_float2(sr, si);
    }
}

// ---------------- kernel 3 (Pass B): full scan per chunk, fused epilogue ----------------
__global__ __launch_bounds__(256) void scan_full_kernel(
        const float* __restrict__ u, const float* __restrict__ a,
        const float* __restrict__ th, const float* __restrict__ bb,
        const float* __restrict__ cc, const float* __restrict__ Dp,
        const float2* __restrict__ FK, const float2* __restrict__ SC,
        __hip_bfloat16* __restrict__ yT) {
    int c = blockIdx.x;                       // 0..15
    int b = blockIdx.z;                       // 0..7
    int h = blockIdx.y * 256 + threadIdx.x;   // 0..511
    int bh = b * H_ + h;
    const float T = 1.0f / (float)(L_ - 1);

    float wr[D2_], wi[D2_], q[D2_], sr[D2_], si[D2_];
    float qsum = 0.f;
    #pragma unroll
    for (int d = 0; d < D2_; ++d) {
        float aa = -fabsf(a[h * D2_ + d]);
        float ea = __expf(aa * T);
        float tT = th[h * D2_ + d] * T;
        wr[d] = ea * __cosf(tT);
        wi[d] = ea * __sinf(tT);
        q[d]  = bb[h * D2_ + d] * cc[h * D2_ + d];
        qsum += q[d];
    }
    float f0 = 2.0f * T * qsum;               // f[h,0]

    #pragma unroll
    for (int d = 0; d < D2_; ++d) {
        if (c == 0) { sr[d] = 0.f; si[d] = 0.f; }
        else {
            float2 s = SC[((size_t)bh * NC_ + c) * D2_ + d];
            sr[d] = s.x; si[d] = s.y;
        }
    }

    float u0 = u[(size_t)bh * L_];
    float Dh = Dp[h];
    const float*  ur  = u  + (size_t)bh * L_ + c * LC_;
    const float2* fkr = FK + (size_t)h  * L_ + c * LC_;
    __hip_bfloat16* yr = yT + ((size_t)b * L_ + c * LC_) * H_ + h;

    for (int i = 0; i < LC_; ++i) {
        float ul = ur[i];
        float2 fk = fkr[i];
        float dta[4] = {0.f, 0.f, 0.f, 0.f};
        #pragma unroll
        for (int d = 0; d < D2_; ++d) {
            float nr = fmaf(sr[d], wr[d], fmaf(-si[d], wi[d], ul));
            float ni = fmaf(sr[d], wi[d], si[d] * wr[d]);
            sr[d] = nr; si[d] = ni;
            dta[d & 3] = fmaf(q[d], nr, dta[d & 3]);
        }
        float dot = (dta[0] + dta[1]) + (dta[2] + dta[3]);
        float y = fmaf(2.0f * T, dot, fk.y)           // conv + k0
                  - 0.5f * (f0 * ul + fk.x * u0)      // trapezoid correction
                  + Dh * ul;                          // skip D*u
        yr[(size_t)i * H_] = __float2bfloat16(gelu_exact(y));
    }
}

// ---------------- kernel 4: out[b,h,l] = sum_f W[h,f] * yT[b,l,f] + bias[h] ----------------
__global__ __launch_bounds__(256) void gemm_kernel(
        const __hip_bfloat16* __restrict__ Wb, const __hip_bfloat16* __restrict__ yT,
        const float* __restrict__ bias, float* __restrict__ out) {
    __shared__ __align__(16) short As[128 * 32];
    __shared__ __align__(16) short Bs[128 * 32];
    int l0 = blockIdx.x * 128;      // N tile
    int h0 = blockIdx.y * 128;      // M tile
    int b  = blockIdx.z;
    int t    = threadIdx.x;
    int lane = t & 63, wave = t >> 6;
    int m_off = (wave >> 1) * 64, n_off = (wave & 1) * 64;
    int quad = lane >> 4, ln = lane & 15;

    float4v acc[4][4];
    #pragma unroll
    for (int mt = 0; mt < 4; ++mt)
        #pragma unroll
        for (int nt = 0; nt < 4; ++nt)
            acc[mt][nt] = (float4v){0.f, 0.f, 0.f, 0.f};

    const short* Wg = (const short*)Wb;
    const short* Yg = (const short*)(yT + (size_t)b * L_ * H_);

    int r  = t >> 2;      // 0..63
    int qd = t & 3;       // 16B chunk within 64B row

    for (int kt = 0; kt < 16; ++kt) {
        int k0 = kt * 32;
        ((uint4*)As)[r * 4 + qd]        = *(const uint4*)(Wg + (h0 + r)      * 512 + k0 + qd * 8);
        ((uint4*)As)[(r + 64) * 4 + qd] = *(const uint4*)(Wg + (h0 + r + 64) * 512 + k0 + qd * 8);
        ((uint4*)Bs)[r * 4 + qd]        = *(const uint4*)(Yg + (size_t)(l0 + r)      * 512 + k0 + qd * 8);
        ((uint4*)Bs)[(r + 64) * 4 + qd] = *(const uint4*)(Yg + (size_t)(l0 + r + 64) * 512 + k0 + qd * 8);
        __syncthreads();

        short8 af[4], bf[4];
        #pragma unroll
        for (int mt = 0; mt < 4; ++mt)
            af[mt] = *(const short8*)&As[(m_off + mt * 16 + ln) * 32 + quad * 8];
        #pragma unroll
        for (int nt = 0; nt < 4; ++nt)
            bf[nt] = *(const short8*)&Bs[(n_off + nt * 16 + ln) * 32 + quad * 8];
        #pragma unroll
        for (int mt = 0; mt < 4; ++mt)
            #pragma unroll
            for (int nt = 0; nt < 4; ++nt)
                acc[mt][nt] = __builtin_amdgcn_mfma_f32_16x16x32_bf16(
                    af[mt], bf[nt], acc[mt][nt], 0, 0, 0);
        __syncthreads();
    }

    #pragma unroll
    for (int mt = 0; mt < 4; ++mt) {
        #pragma unroll
        for (int nt = 0; nt < 4; ++nt) {
            int hh = h0 + m_off + mt * 16 + quad * 4;
            int ll = l0 + n_off + nt * 16 + ln;
            #pragma unroll
            for (int r2 = 0; r2 < 4; ++r2)
                out[((size_t)(b * H_ + hh + r2)) * L_ + ll] = acc[mt][nt][r2] + bias[hh + r2];
        }
    }
}

extern "C" void kernel_launch(void* const* d_in, const int* in_sizes, int n_in,
                              void* d_out, int out_size, void* d_ws, size_t ws_size,
                              hipStream_t stream) {
    const float* u    = (const float*)d_in[0];
    const float* a    = (const float*)d_in[1];
    const float* th   = (const float*)d_in[2];
    const float* bb   = (const float*)d_in[3];
    const float* cc   = (const float*)d_in[4];
    const float* x0   = (const float*)d_in[5];
    const float* Dp   = (const float*)d_in[6];
    const float* W    = (const float*)d_in[7];
    const float* bias = (const float*)d_in[8];
    float* out = (float*)d_out;

    char* ws = (char*)d_ws;
    // FK: 512*2048*8B  = 8 MB   [0, 8MB)
    // SC: 8*512*16*32*8B = 16 MB [8MB, 24MB)
    // E:  16 MB [24MB, 40MB)  -- aliased with yT (E dead before Pass B writes yT)
    // yT: 8*2048*512*2B = 16 MB [24MB, 40MB)
    // Wb: 0.5 MB [40MB, 40.5MB)
    float2* FK          = (float2*)ws;
    float2* SC          = (float2*)(ws + 8u  * 1024 * 1024);
    float2* E           = (float2*)(ws + 24u * 1024 * 1024);
    __hip_bfloat16* yT  = (__hip_bfloat16*)(ws + 24u * 1024 * 1024);
    __hip_bfloat16* Wb  = (__hip_bfloat16*)(ws + 40u * 1024 * 1024);

    hipLaunchKernelGGL(cast_w_kernel,     dim3(1024),     dim3(256), 0, stream, W, Wb);
    hipLaunchKernelGGL(fk_kernel,         dim3(4096),     dim3(256), 0, stream, a, th, bb, cc, x0, FK);
    hipLaunchKernelGGL(scan_chunk_kernel, dim3(8192),     dim3(256), 0, stream, u, a, th, E);
    hipLaunchKernelGGL(combine_kernel,    dim3(512),      dim3(256), 0, stream, a, th, E, SC);
    hipLaunchKernelGGL(scan_full_kernel,  dim3(16, 2, 8), dim3(256), 0, stream,
                       u, a, th, bb, cc, Dp, FK, SC, yT);
    hipLaunchKernelGGL(gemm_kernel,       dim3(16, 4, 8), dim3(256), 0, stream, Wb, yT, bias, out);
}